// Round 6
// baseline (150.369 us; speedup 1.0000x reference)
//
#include <hip/hip_runtime.h>
#include <math.h>

#define M_GRID 128
#define J_FEAT 80
#define NNET   160   // NBASE*J_FEAT
#define HDIM   256

typedef __attribute__((ext_vector_type(8))) short v8s;  // 8 bf16
typedef __attribute__((ext_vector_type(4))) float f4;   // MFMA accum

__device__ __forceinline__ unsigned short f2bf(float f) {
    unsigned u = __float_as_uint(f);
    u += 0x7fffu + ((u >> 16) & 1u);   // round-to-nearest-even
    return (unsigned short)(u >> 16);
}

__device__ __forceinline__ float selu_f(float x) {
    const float SC = 1.0507009873554805f;
    const float AL = 1.6732632423543772f;
    return x > 0.f ? SC * x : SC * AL * (__expf(x) - 1.f);
}

// One workgroup per network n, 512 threads (8 waves), wave w owns rows 16w..16w+15.
// Per layer: 8 K-stages of 32 k-rows. Stage s: fp32 W rows staged by
// global_load_lds dwordx4 (zero VGPRs) into 32 KB buf (s&1) (double-buffered,
// issued 2 stages ahead = 64 KB in flight); cooperative convert+transpose to
// XOR-swizzled bf16 tile (s&1); 16 ds_read_b128 + 16 MFMA per wave.
// Sync per stage: own-wave vmcnt(4) -> barrier (all DMAs of stage s landed)
// -> convert -> lgkmcnt(0) -> barrier (tile visible) -> issue s+2 -> MFMA.
// No __syncthreads in the K-loop (would drain vmcnt and kill the pipeline).
// Spill avoidance is load-bearing: scratch ops would corrupt vmcnt counts.
// Input layer uses recompute (two 8-reg passes) to keep peak pressure low.
// LDS 96 KiB dynamic: fp32 bufs 2x32K @0 (reused as per-wave 8K scr between
// layers), bf16 tiles 2x16K @65536.
__attribute__((amdgpu_flat_work_group_size(512, 512), amdgpu_waves_per_eu(1, 2)))
__global__ void basis_kernel(const float* __restrict__ t,
                             const float* __restrict__ W_in,
                             const float* __restrict__ b_in,
                             const float* __restrict__ W_h,
                             const float* __restrict__ b_h,
                             const float* __restrict__ W_out,
                             const float* __restrict__ b_out,
                             const float* __restrict__ ln_a,
                             const float* __restrict__ ln_b,
                             float* __restrict__ basesT)   // [M][NNET]
{
    extern __shared__ __align__(16) unsigned char lds[];   // 96 KiB
    const int n   = blockIdx.x;
    const int tid = threadIdx.x;
    const int l   = tid & 63;
    const int wv  = tid >> 6;      // wave 0..7
    const int lr  = l & 15;
    const int g   = l >> 4;        // k-group
    const int jj  = tid & 255;     // convert-pass column
    const int oo  = tid >> 8;      // convert-pass k-octet (0/1)

    // ---------------- input layer (recompute; bit-identical FMA both passes) ----
    const float tval = t[wv * 16 + lr];
    v8s afrag[8];
    {
        const float* wi = W_in + (size_t)n * HDIM;
        const float* bi = b_in + (size_t)n * HDIM;
        float s = 0.f, q = 0.f;
        #pragma unroll
        for (int kt = 0; kt < 8; ++kt) {
            const int h0 = kt * 32 + g * 8;
            #pragma unroll
            for (int i = 0; i < 8; ++i) {
                float v = __builtin_fmaf(tval, wi[h0 + i], bi[h0 + i]);
                s += v; q += v * v;
            }
        }
        s += __shfl_xor(s, 16); q += __shfl_xor(q, 16);
        s += __shfl_xor(s, 32); q += __shfl_xor(q, 32);
        const float mean = s * (1.f / 256.f);
        const float var  = (q - s * s * (1.f / 256.f)) * (1.f / 255.f); // unbiased
        const float inv  = 1.f / (sqrtf(var) + 1e-6f);                  // eps on std
        const float* la = ln_a + (size_t)n * HDIM;
        const float* lb = ln_b + (size_t)n * HDIM;
        #pragma unroll
        for (int kt = 0; kt < 8; ++kt) {
            const int h0 = kt * 32 + g * 8;
            v8s a;
            #pragma unroll
            for (int i = 0; i < 8; ++i) {
                float v   = __builtin_fmaf(tval, wi[h0 + i], bi[h0 + i]);
                float lnv = (v - mean) * inv * la[h0 + i] + lb[h0 + i];
                a[i] = (short)f2bf(selu_f(v + lnv));
            }
            afrag[kt] = a;
        }
    }

    unsigned char* const scr = lds + (size_t)wv * 8192;  // inter-layer scratch

    f4 acc[16];

    #pragma unroll 1
    for (int L = 0; L < 3; ++L) {
        const float* Wl = W_h + ((size_t)L * NNET + n) * (HDIM * HDIM);

        const f4 zero = {0.f, 0.f, 0.f, 0.f};
        #pragma unroll
        for (int ct = 0; ct < 16; ++ct) {
            acc[ct] = zero;
            asm volatile("" : "+a"(acc[ct]));   // pin to AGPR side
        }

        // stage s: 32 k-rows x 256 j fp32 -> buf (s&1). Wave wv: rows 4wv..4wv+3,
        // 1 KB each via one global_load_lds dwordx4 (lane-contiguous).
        auto issue_stage = [&](int s) {
            unsigned char* dst = lds + (size_t)(s & 1) * 32768;
            #pragma unroll
            for (int i = 0; i < 4; ++i) {
                const int r = wv * 4 + i;
                const float* gp = Wl + (size_t)(s * 32 + r) * HDIM + (l << 2);
                __builtin_amdgcn_global_load_lds(
                    (const __attribute__((address_space(1))) void*)gp,
                    (__attribute__((address_space(3))) void*)(dst + (size_t)r * 1024),
                    16, 0, 0);
            }
        };
        // convert stage s: fp32 [32k][256j] buf (s&1) -> bf16 tile (s&1),
        // layout [256j][16k] x 2 k-halves, XOR-swizzled. Thread: col jj, octet oo.
        auto convert_stage = [&](int s) {
            const unsigned char* src = lds + (size_t)(s & 1) * 32768;
            const int tb = 65536 + ((s & 1) << 14);
            #pragma unroll
            for (int h = 0; h < 2; ++h) {
                v8s pk;
                #pragma unroll
                for (int i = 0; i < 8; ++i) {
                    const int k = h * 16 + oo * 8 + i;
                    pk[i] = (short)f2bf(*(const float*)(src + ((size_t)k << 10) + (jj << 2)));
                }
                int byte = tb + h * 8192 + jj * 32 + oo * 16;
                byte ^= ((jj >> 2) & 7) << 4;
                *(v8s*)(lds + byte) = pk;
            }
        };

        issue_stage(0);
        issue_stage(1);

        #pragma unroll
        for (int s = 0; s < 8; ++s) {
            // wait own DMAs for stage s (4 newer in flight), then sync: after the
            // barrier ALL waves' stage-s DMAs have landed.
            if (s < 7) asm volatile("s_waitcnt vmcnt(4)" ::: "memory");
            else       asm volatile("s_waitcnt vmcnt(0)" ::: "memory");
            __builtin_amdgcn_s_barrier();
            convert_stage(s);
            asm volatile("s_waitcnt lgkmcnt(0)" ::: "memory");
            __builtin_amdgcn_s_barrier();          // tile (s&1) visible; fp32 buf free
            if (s < 6) issue_stage(s + 2);         // refill the buf just converted
            // MFMA stage s from bf16 tile (s&1)
            #pragma unroll
            for (int ct = 0; ct < 16; ++ct) {
                const int jb = ct * 16 + lr;
                int byte = 65536 + ((s & 1) << 14) + ((g >> 1) << 13)
                         + jb * 32 + ((g & 1) << 4);
                byte ^= ((jb >> 2) & 7) << 4;
                const v8s bf = *(const v8s*)(lds + byte);
                acc[ct] = __builtin_amdgcn_mfma_f32_16x16x32_bf16(
                    afrag[s], bf, acc[ct], 0, 0, 0);
            }
        }

        // ---------------- epilogue ----------------
        const float* bh = b_h  + ((size_t)L * NNET + n) * HDIM;
        const float* la = ln_a + ((size_t)(L + 1) * NNET + n) * HDIM;
        const float* lb = ln_b + ((size_t)(L + 1) * NNET + n) * HDIM;

        float sums[4] = {0,0,0,0}, sqs[4] = {0,0,0,0};
        #pragma unroll
        for (int ct = 0; ct < 16; ++ct) {
            const float bias = bh[ct * 16 + lr];
            #pragma unroll
            for (int r = 0; r < 4; ++r) {
                float v = acc[ct][r] + bias;
                acc[ct][r] = v;
                sums[r] += v; sqs[r] += v * v;
            }
        }
        #pragma unroll
        for (int r = 0; r < 4; ++r)
            #pragma unroll
            for (int m = 1; m <= 8; m <<= 1) {
                sums[r] += __shfl_xor(sums[r], m);
                sqs[r]  += __shfl_xor(sqs[r],  m);
            }
        float mean[4], inv[4];
        #pragma unroll
        for (int r = 0; r < 4; ++r) {
            mean[r] = sums[r] * (1.f / 256.f);
            float var = (sqs[r] - sums[r] * sums[r] * (1.f / 256.f)) * (1.f / 255.f);
            inv[r] = 1.f / (sqrtf(var) + 1e-6f);
        }

        if (L < 2) {
            // C layout (row=4g+r, col=ct*16+lr) -> per-wave scr -> A-fragments.
            // scr aliases fp32 bufs; safe: all DMAs drained (vmcnt(0) at s=7 in
            // every wave before the last barrier), tile region is disjoint.
            #pragma unroll
            for (int ct = 0; ct < 16; ++ct) {
                const float a_ = la[ct * 16 + lr], b_ = lb[ct * 16 + lr];
                #pragma unroll
                for (int r = 0; r < 4; ++r) {
                    float v  = acc[ct][r];
                    float sv = selu_f(v + (v - mean[r]) * inv[r] * a_ + b_);
                    const int row  = 4 * g + r;
                    const int byte = (row * 512 + (ct * 16 + lr) * 2) ^ (row << 5);
                    *(unsigned short*)(scr + byte) = f2bf(sv);
                }
            }
            asm volatile("s_waitcnt lgkmcnt(0)" ::: "memory");  // own writes done
            #pragma unroll
            for (int kt = 0; kt < 8; ++kt) {
                const int byte = (lr * 512 + (kt * 32 + g * 8) * 2) ^ (lr << 5);
                afrag[kt] = *(const v8s*)(scr + byte);
            }
            __syncthreads();   // all scr reads done before next layer's DMA refill
        } else {
            // fused output layer
            const float* wo = W_out + (size_t)n * HDIM;
            const float bo  = b_out[n];
            float ps[4] = {0,0,0,0};
            #pragma unroll
            for (int ct = 0; ct < 16; ++ct) {
                const float a_ = la[ct * 16 + lr], b_ = lb[ct * 16 + lr];
                const float w_ = wo[ct * 16 + lr];
                #pragma unroll
                for (int r = 0; r < 4; ++r) {
                    float v  = acc[ct][r];
                    float sv = selu_f(v + (v - mean[r]) * inv[r] * a_ + b_);
                    ps[r] += sv * w_;
                }
            }
            #pragma unroll
            for (int r = 0; r < 4; ++r)
                #pragma unroll
                for (int m = 1; m <= 8; m <<= 1)
                    ps[r] += __shfl_xor(ps[r], m);
            #pragma unroll
            for (int r = 0; r < 4; ++r)
                if (lr == r)
                    basesT[(size_t)(wv * 16 + 4 * g + r) * NNET + n] = ps[r] + bo;
        }
    }
}

// score[b, jk] = sum_m x[b,m,jk>>1] * basesT[m][jk] * w[m]
__launch_bounds__(256)
__global__ void score_kernel(const float* __restrict__ x,
                             const float* __restrict__ t,
                             const float* __restrict__ basesT,
                             float* __restrict__ out)
{
    __shared__ float c_lds[M_GRID * 32];
    const int jt  = blockIdx.x;   // 0..4
    const int bt  = blockIdx.y;   // 0..255
    const int tid = threadIdx.x;

    for (int i = tid; i < M_GRID * 32; i += 256) {
        const int m  = i >> 5;
        const int jl = i & 31;
        const float tp = t[m == M_GRID - 1 ? M_GRID - 1 : m + 1];
        const float tm = t[m == 0 ? 0 : m - 1];
        c_lds[i] = basesT[(size_t)m * NNET + jt * 32 + jl] * 0.5f * (tp - tm);
    }
    __syncthreads();

    const int jj = tid & 31;
    const int bs = tid >> 5;
    const int jk = jt * 32 + jj;
    const int b  = bt * 8 + bs;
    const float* xp = x + (size_t)b * (M_GRID * J_FEAT) + (jk >> 1);
    float acc = 0.f;
    #pragma unroll 8
    for (int m = 0; m < M_GRID; ++m)
        acc += xp[(size_t)m * J_FEAT] * c_lds[m * 32 + jj];
    out[(size_t)b * NNET + jk] = acc;
}

extern "C" void kernel_launch(void* const* d_in, const int* in_sizes, int n_in,
                              void* d_out, int out_size, void* d_ws, size_t ws_size,
                              hipStream_t stream)
{
    const float* x     = (const float*)d_in[0];
    const float* t     = (const float*)d_in[1];
    const float* W_in  = (const float*)d_in[2];
    const float* b_in  = (const float*)d_in[3];
    const float* W_h   = (const float*)d_in[4];
    const float* b_h   = (const float*)d_in[5];
    const float* W_out = (const float*)d_in[6];
    const float* b_out = (const float*)d_in[7];
    const float* ln_a  = (const float*)d_in[8];
    const float* ln_b  = (const float*)d_in[9];
    float* basesT = (float*)d_ws;   // 128*160*4 = 80 KiB

    basis_kernel<<<dim3(NNET), dim3(512), 98304, stream>>>(
        t, W_in, b_in, W_h, b_h, W_out, b_out, ln_a, ln_b, basesT);
    score_kernel<<<dim3(5, 256), dim3(256), 0, stream>>>(
        x, t, basesT, (float*)d_out);
}

// Round 7
// 130.854 us; speedup vs baseline: 1.1491x; 1.1491x over previous
//
#include <hip/hip_runtime.h>
#include <math.h>

#define M_GRID 128
#define J_FEAT 80
#define NNET   160   // NBASE*J_FEAT
#define HDIM   256

typedef __attribute__((ext_vector_type(8))) short v8s;  // 8 bf16
typedef __attribute__((ext_vector_type(4))) float f4;   // MFMA accum

__device__ __forceinline__ unsigned short f2bf(float f) {
    unsigned u = __float_as_uint(f);
    u += 0x7fffu + ((u >> 16) & 1u);   // round-to-nearest-even
    return (unsigned short)(u >> 16);
}

__device__ __forceinline__ float selu_f(float x) {
    const float SC = 1.0507009873554805f;
    const float AL = 1.6732632423543772f;
    return x > 0.f ? SC * x : SC * AL * (__expf(x) - 1.f);
}

// One workgroup per network n, 256 threads = 4 waves, 1 wave/SIMD.
// Rationale (rounds 1-6): a 512-thread block means 2 waves/SIMD and a hard
// ~256-reg unified budget -> unavoidable spills in the K-loop, whose scratch
// VMEM both serialized every stage and corrupted counted vmcnt waits. At 4
// waves the budget is ~512: afragA/B (64 VGPR) + acc[2][16] (128 AGPR) +
// working set fit with room to spare.
// Wave w owns rows 32w..32w+31 as two 16-row MFMA tiles (A/B); one B-fragment
// ds_read feeds 2 MFMAs. Weights: global_load_lds dwordx4 into fp32 bufs
// 2x32KB (double-buffered, 2 stages = 64KB in flight, counted vmcnt(8));
// cooperative convert to XOR-swizzled bf16 tiles 2x16KB; 2 raw s_barriers +
// 1 lgkmcnt per stage; NO __syncthreads anywhere in/between K-loops (would
// drain vmcnt). Inter-layer C->A transpose: per-wave 8KB scr region == that
// wave's own DMA slice of buf0, so only per-wave lgkmcnt ordering is needed.
// LDS 96 KiB dynamic: fp32 bufs @0 (2x32K), bf16 tiles @65536 (2x16K).
__attribute__((amdgpu_flat_work_group_size(256, 256), amdgpu_waves_per_eu(1, 1)))
__global__ void basis_kernel(const float* __restrict__ t,
                             const float* __restrict__ W_in,
                             const float* __restrict__ b_in,
                             const float* __restrict__ W_h,
                             const float* __restrict__ b_h,
                             const float* __restrict__ W_out,
                             const float* __restrict__ b_out,
                             const float* __restrict__ ln_a,
                             const float* __restrict__ ln_b,
                             float* __restrict__ basesT)   // [M][NNET]
{
    extern __shared__ __align__(16) unsigned char lds[];   // 96 KiB
    const int n   = blockIdx.x;
    const int tid = threadIdx.x;
    const int l   = tid & 63;
    const int wv  = tid >> 6;      // wave 0..3
    const int lr  = l & 15;
    const int g   = l >> 4;        // k-group
    const int jj  = tid;           // convert-pass column 0..255

    // ---------------- input layer (recompute, two 16-row tiles per wave) -------
    v8s afragA[8], afragB[8];
    {
        const float* wi = W_in + (size_t)n * HDIM;
        const float* bi = b_in + (size_t)n * HDIM;
        const float* la = ln_a + (size_t)n * HDIM;
        const float* lb = ln_b + (size_t)n * HDIM;
        auto input_tile = [&](float tval, v8s (&af)[8]) {
            float s = 0.f, q = 0.f;
            #pragma unroll
            for (int kt = 0; kt < 8; ++kt) {
                const int h0 = kt * 32 + g * 8;
                #pragma unroll
                for (int i = 0; i < 8; ++i) {
                    float v = __builtin_fmaf(tval, wi[h0 + i], bi[h0 + i]);
                    s += v; q += v * v;
                }
            }
            s += __shfl_xor(s, 16); q += __shfl_xor(q, 16);
            s += __shfl_xor(s, 32); q += __shfl_xor(q, 32);
            const float mean = s * (1.f / 256.f);
            const float var  = (q - s * s * (1.f / 256.f)) * (1.f / 255.f); // unbiased
            const float inv  = 1.f / (sqrtf(var) + 1e-6f);                  // eps on std
            #pragma unroll
            for (int kt = 0; kt < 8; ++kt) {
                const int h0 = kt * 32 + g * 8;
                v8s a;
                #pragma unroll
                for (int i = 0; i < 8; ++i) {
                    float v   = __builtin_fmaf(tval, wi[h0 + i], bi[h0 + i]);
                    float lnv = (v - mean) * inv * la[h0 + i] + lb[h0 + i];
                    a[i] = (short)f2bf(selu_f(v + lnv));
                }
                af[kt] = a;
            }
        };
        input_tile(t[wv * 32 + lr],      afragA);
        input_tile(t[wv * 32 + 16 + lr], afragB);
    }

    unsigned char* const scr = lds + (size_t)wv * 8192;  // == own DMA slice of buf0

    f4 acc[2][16];

    #pragma unroll 1
    for (int L = 0; L < 3; ++L) {
        const float* Wl = W_h + ((size_t)L * NNET + n) * (HDIM * HDIM);

        const f4 zero = {0.f, 0.f, 0.f, 0.f};
        #pragma unroll
        for (int tt = 0; tt < 2; ++tt)
            #pragma unroll
            for (int ct = 0; ct < 16; ++ct) {
                acc[tt][ct] = zero;
                asm volatile("" : "+a"(acc[tt][ct]));   // pin to AGPR side
            }

        // stage s: 32 k-rows x 256 j fp32 -> buf (s&1). Wave wv: rows 8wv..8wv+7,
        // 1 KB each via one global_load_lds dwordx4 (lane-contiguous).
        auto issue_stage = [&](int s) {
            unsigned char* dst = lds + (size_t)(s & 1) * 32768;
            #pragma unroll
            for (int i = 0; i < 8; ++i) {
                const int r = wv * 8 + i;
                const float* gp = Wl + (size_t)(s * 32 + r) * HDIM + (l << 2);
                __builtin_amdgcn_global_load_lds(
                    (const __attribute__((address_space(1))) void*)gp,
                    (__attribute__((address_space(3))) void*)(dst + (size_t)r * 1024),
                    16, 0, 0);
            }
        };
        // convert stage s: fp32 [32k][256j] buf (s&1) -> bf16 tile (s&1),
        // layout [256j][16k] x 2 k-halves, XOR-swizzled. Thread: column jj.
        auto convert_stage = [&](int s) {
            const unsigned char* src = lds + (size_t)(s & 1) * 32768;
            const int tb = 65536 + ((s & 1) << 14);
            #pragma unroll
            for (int h = 0; h < 2; ++h)
                #pragma unroll
                for (int o = 0; o < 2; ++o) {
                    v8s pk;
                    #pragma unroll
                    for (int i = 0; i < 8; ++i) {
                        const int k = h * 16 + o * 8 + i;
                        pk[i] = (short)f2bf(*(const float*)(src + ((size_t)k << 10) + (jj << 2)));
                    }
                    int byte = tb + h * 8192 + jj * 32 + o * 16;
                    byte ^= ((jj >> 2) & 7) << 4;
                    *(v8s*)(lds + byte) = pk;
                }
        };

        issue_stage(0);
        issue_stage(1);

        #pragma unroll
        for (int s = 0; s < 8; ++s) {
            // own 8 DMAs of stage s done (stage s+1's 8 still in flight), then
            // barrier: all waves' stage-s DMAs have landed.
            if (s < 7) asm volatile("s_waitcnt vmcnt(8)" ::: "memory");
            else       asm volatile("s_waitcnt vmcnt(0)" ::: "memory");
            __builtin_amdgcn_s_barrier();
            convert_stage(s);
            asm volatile("s_waitcnt lgkmcnt(0)" ::: "memory");
            __builtin_amdgcn_s_barrier();          // tile (s&1) visible; fp32 buf free
            if (s < 6) issue_stage(s + 2);         // refill the buf just converted
            // MFMA stage s: 16 shared B-fragments feed both row-tiles
            #pragma unroll
            for (int ct = 0; ct < 16; ++ct) {
                const int jb = ct * 16 + lr;
                int byte = 65536 + ((s & 1) << 14) + ((g >> 1) << 13)
                         + jb * 32 + ((g & 1) << 4);
                byte ^= ((jb >> 2) & 7) << 4;
                const v8s bf = *(const v8s*)(lds + byte);
                acc[0][ct] = __builtin_amdgcn_mfma_f32_16x16x32_bf16(
                    afragA[s], bf, acc[0][ct], 0, 0, 0);
                acc[1][ct] = __builtin_amdgcn_mfma_f32_16x16x32_bf16(
                    afragB[s], bf, acc[1][ct], 0, 0, 0);
            }
        }

        // ---------------- epilogue (per wave, both tiles) ----------------
        const float* bh = b_h  + ((size_t)L * NNET + n) * HDIM;
        const float* la = ln_a + ((size_t)(L + 1) * NNET + n) * HDIM;
        const float* lb = ln_b + ((size_t)(L + 1) * NNET + n) * HDIM;

        auto ln_stats = [&](f4 (&A)[16], float (&mean)[4], float (&inv)[4]) {
            float sums[4] = {0,0,0,0}, sqs[4] = {0,0,0,0};
            #pragma unroll
            for (int ct = 0; ct < 16; ++ct) {
                const float bias = bh[ct * 16 + lr];
                #pragma unroll
                for (int r = 0; r < 4; ++r) {
                    float v = A[ct][r] + bias;
                    A[ct][r] = v;
                    sums[r] += v; sqs[r] += v * v;
                }
            }
            #pragma unroll
            for (int r = 0; r < 4; ++r)
                #pragma unroll
                for (int m = 1; m <= 8; m <<= 1) {
                    sums[r] += __shfl_xor(sums[r], m);
                    sqs[r]  += __shfl_xor(sqs[r],  m);
                }
            #pragma unroll
            for (int r = 0; r < 4; ++r) {
                mean[r] = sums[r] * (1.f / 256.f);
                float var = (sqs[r] - sums[r] * sums[r] * (1.f / 256.f)) * (1.f / 255.f);
                inv[r] = 1.f / (sqrtf(var) + 1e-6f);
            }
        };

        if (L < 2) {
            auto mid_tile = [&](f4 (&A)[16], v8s (&af)[8]) {
                float mean[4], inv[4];
                ln_stats(A, mean, inv);
                #pragma unroll
                for (int ct = 0; ct < 16; ++ct) {
                    const float a_ = la[ct * 16 + lr], b_ = lb[ct * 16 + lr];
                    #pragma unroll
                    for (int r = 0; r < 4; ++r) {
                        float v  = A[ct][r];
                        float sv = selu_f(v + (v - mean[r]) * inv[r] * a_ + b_);
                        const int row  = 4 * g + r;
                        const int byte = (row * 512 + (ct * 16 + lr) * 2) ^ (row << 5);
                        *(unsigned short*)(scr + byte) = f2bf(sv);
                    }
                }
                asm volatile("s_waitcnt lgkmcnt(0)" ::: "memory");  // writes done
                #pragma unroll
                for (int kt = 0; kt < 8; ++kt) {
                    const int byte = (lr * 512 + (kt * 32 + g * 8) * 2) ^ (lr << 5);
                    af[kt] = *(const v8s*)(scr + byte);
                }
                asm volatile("s_waitcnt lgkmcnt(0)" ::: "memory");  // reads done
            };
            mid_tile(acc[0], afragA);   // scr is wave-private; reused serially
            mid_tile(acc[1], afragB);
            // next layer's prologue DMAs (issued after this point, same wave)
            // write exactly this wave's scr slice -> per-wave order suffices.
        } else {
            const float* wo = W_out + (size_t)n * HDIM;
            const float bo  = b_out[n];
            auto out_tile = [&](f4 (&A)[16], int tt) {
                float mean[4], inv[4];
                ln_stats(A, mean, inv);
                float ps[4] = {0,0,0,0};
                #pragma unroll
                for (int ct = 0; ct < 16; ++ct) {
                    const float a_ = la[ct * 16 + lr], b_ = lb[ct * 16 + lr];
                    const float w_ = wo[ct * 16 + lr];
                    #pragma unroll
                    for (int r = 0; r < 4; ++r) {
                        float v  = A[ct][r];
                        float sv = selu_f(v + (v - mean[r]) * inv[r] * a_ + b_);
                        ps[r] += sv * w_;
                    }
                }
                #pragma unroll
                for (int r = 0; r < 4; ++r)
                    #pragma unroll
                    for (int m = 1; m <= 8; m <<= 1)
                        ps[r] += __shfl_xor(ps[r], m);
                #pragma unroll
                for (int r = 0; r < 4; ++r)
                    if (lr == r)
                        basesT[(size_t)(wv * 32 + tt * 16 + 4 * g + r) * NNET + n] = ps[r] + bo;
            };
            out_tile(acc[0], 0);
            out_tile(acc[1], 1);
        }
    }
}

// score[b, jk] = sum_m x[b,m,jk>>1] * basesT[m][jk] * w[m]
__launch_bounds__(256)
__global__ void score_kernel(const float* __restrict__ x,
                             const float* __restrict__ t,
                             const float* __restrict__ basesT,
                             float* __restrict__ out)
{
    __shared__ float c_lds[M_GRID * 32];
    const int jt  = blockIdx.x;   // 0..4
    const int bt  = blockIdx.y;   // 0..255
    const int tid = threadIdx.x;

    for (int i = tid; i < M_GRID * 32; i += 256) {
        const int m  = i >> 5;
        const int jl = i & 31;
        const float tp = t[m == M_GRID - 1 ? M_GRID - 1 : m + 1];
        const float tm = t[m == 0 ? 0 : m - 1];
        c_lds[i] = basesT[(size_t)m * NNET + jt * 32 + jl] * 0.5f * (tp - tm);
    }
    __syncthreads();

    const int jj = tid & 31;
    const int bs = tid >> 5;
    const int jk = jt * 32 + jj;
    const int b  = bt * 8 + bs;
    const float* xp = x + (size_t)b * (M_GRID * J_FEAT) + (jk >> 1);
    float acc = 0.f;
    #pragma unroll 8
    for (int m = 0; m < M_GRID; ++m)
        acc += xp[(size_t)m * J_FEAT] * c_lds[m * 32 + jj];
    out[(size_t)b * NNET + jk] = acc;
}

extern "C" void kernel_launch(void* const* d_in, const int* in_sizes, int n_in,
                              void* d_out, int out_size, void* d_ws, size_t ws_size,
                              hipStream_t stream)
{
    const float* x     = (const float*)d_in[0];
    const float* t     = (const float*)d_in[1];
    const float* W_in  = (const float*)d_in[2];
    const float* b_in  = (const float*)d_in[3];
    const float* W_h   = (const float*)d_in[4];
    const float* b_h   = (const float*)d_in[5];
    const float* W_out = (const float*)d_in[6];
    const float* b_out = (const float*)d_in[7];
    const float* ln_a  = (const float*)d_in[8];
    const float* ln_b  = (const float*)d_in[9];
    float* basesT = (float*)d_ws;   // 128*160*4 = 80 KiB

    basis_kernel<<<dim3(NNET), dim3(256), 98304, stream>>>(
        t, W_in, b_in, W_h, b_h, W_out, b_out, ln_a, ln_b, basesT);
    score_kernel<<<dim3(5, 256), dim3(256), 0, stream>>>(
        x, t, basesT, (float*)d_out);
}